// Round 15
// baseline (126.918 us; speedup 1.0000x reference)
//
#include <hip/hip_runtime.h>
#include <math.h>

#define NN 100000     // nodes
#define NE 3200000    // edges
#define NG 64         // graphs
#define HID 16
#define EPB 4096                          // edges per block in bucket pipeline
#define NBLKE ((NE + EPB - 1) / EPB)      // 782 edge blocks
#define NBUCK ((NN + 255) / 256)          // 391 buckets (256 nodes each)
#define LMAX 10240                        // per-bucket LDS sorted-src capacity

typedef unsigned int uint;
typedef float vf2 __attribute__((ext_vector_type(2)));

// ---------------- workspace layout (4-byte units) ----------------
// gsum      [0, NG)                     float  (zeroed by k_scan)
// gcnt      [NG, 2NG)                   float  (zeroed by k_scan)
// blockCnt  [2NG, +NBUCK*NBLKE)         int    (layout [bucket][blk])
// bucketTot [.., +NBUCK)                int    (memset 0; bhist atomicAdd)
// bucketBase[.., +NBUCK+1)              int
// offs      [.., +NN+1)                 int    (node CSR offsets; [NN]=NE sentinel)
// pad to 16B
// pairs     [.., +NE)                   int    ((src<<8)|dst_low8, bucket-sorted)
// csr       [.., +NE)                   int    (src ids grouped by dst)
// h8        [.., +4*NN)                 uint   (h1 relu'd, fp8 e4m3 x16, 16B/row)
//
// LESSONS: no __threadfence in hot kernels (r9: device-scope L2 writeback,
// +100us); no nontemporal stores on randomly-ordered fills (r10: 13x write
// amplification); nt loads net-negative (r11). Block-local sort (r12/r13)
// loses to global 2-level sort. Keep csr stores OUT of the atomic fill loop
// (stream coalesced from LDS instead).

// ---------- fp8 e4m3 helpers (HW builtins; word-select must be literal) ----------
template <bool HI>
__device__ inline vf2 dec2fp8(uint u) {
#if __has_builtin(__builtin_amdgcn_cvt_pk_f32_fp8)
    return __builtin_amdgcn_cvt_pk_f32_fp8((int)u, HI);
#else
    vf2 r;
    uint b0 = (u >> (HI ? 16 : 0)) & 0xff;
    uint b1 = (u >> (HI ? 24 : 8)) & 0xff;
    uint em0 = b0 & 0x7f, em1 = b1 & 0x7f;
    float v0 = (em0 >= 8) ? __uint_as_float(((em0 >> 3) + 120) << 23 | (em0 & 7) << 20)
                          : (float)em0 * 0.001953125f;
    float v1 = (em1 >= 8) ? __uint_as_float(((em1 >> 3) + 120) << 23 | (em1 & 7) << 20)
                          : (float)em1 * 0.001953125f;
    r.x = (b0 & 0x80) ? -v0 : v0;
    r.y = (b1 & 0x80) ? -v1 : v1;
    return r;
#endif
}

__device__ inline uint enc1fp8(float f) {   // f >= 0 (post-relu)
    if (!(f > 0.f)) return 0u;
    f = fminf(f, 448.f);
    uint b = __float_as_uint(f);
    int e = (int)(b >> 23) - 127;
    if (e >= -6) {
        uint m = b & 0x7fffffu;
        uint r = (m + 0x7ffffu + ((m >> 20) & 1u)) >> 20;   // RNE to 3 bits
        uint code = ((uint)(e + 7) << 3) + r;
        return code > 126u ? 126u : code;
    }
    float t = f * 512.f;
    return (uint)(t + 0.5f);
}

template <bool HI>
__device__ inline uint packfp8x2(float a, float b, uint old) {
#if __has_builtin(__builtin_amdgcn_cvt_pk_fp8_f32)
    return (uint)__builtin_amdgcn_cvt_pk_fp8_f32(a, b, (int)old, HI);
#else
    uint v = enc1fp8(a) | (enc1fp8(b) << 8);
    return HI ? ((old & 0x0000ffffu) | (v << 16)) : ((old & 0xffff0000u) | v);
#endif
}

__global__ __launch_bounds__(512) void k_bhist(const int* __restrict__ dst,
                                               int* __restrict__ blockCnt,
                                               int* __restrict__ bucketTot) {
    __shared__ int h[NBUCK];
    int t = threadIdx.x;
    for (int i = t; i < NBUCK; i += 512) h[i] = 0;
    __syncthreads();
    int base = blockIdx.x * EPB;
    int n4 = (min(base + EPB, NE) - base) >> 2;       // 4096 and 1024 both /4
    const int4* d4 = (const int4*)(dst + base);
    for (int i = t; i < n4; i += 512) {
        int4 v = d4[i];
        atomicAdd(&h[v.x >> 8], 1);
        atomicAdd(&h[v.y >> 8], 1);
        atomicAdd(&h[v.z >> 8], 1);
        atomicAdd(&h[v.w >> 8], 1);
    }
    __syncthreads();
    for (int i = t; i < NBUCK; i += 512) {
        int hv = h[i];
        blockCnt[i * NBLKE + blockIdx.x] = hv;         // [bucket][blk]
        if (hv) atomicAdd(&bucketTot[i], hv);          // int sum: deterministic
    }
}

// blocks 0..NBUCK-1: per-bucket exclusive prefix over the 782 edge-blocks.
// block NBUCK: exclusive scan of bucketTot -> bucketBase (+sentinels, +zeroing).
__global__ __launch_bounds__(1024) void k_scan(int* __restrict__ blockCnt,
                                               const int* __restrict__ bucketTot,
                                               int* __restrict__ bucketBase,
                                               int* __restrict__ offs,
                                               float* __restrict__ gsum,
                                               float* __restrict__ gcnt) {
    __shared__ int a[1024];
    int t = threadIdx.x, b = blockIdx.x;
    if (b < NBUCK) {
        a[t] = (t < NBLKE) ? blockCnt[b * NBLKE + t] : 0;  // coalesced
        __syncthreads();
        for (int off = 1; off < 1024; off <<= 1) {
            int x = a[t] + ((t >= off) ? a[t - off] : 0);
            __syncthreads();
            a[t] = x;
            __syncthreads();
        }
        if (t < NBLKE) blockCnt[b * NBLKE + t] = (t ? a[t - 1] : 0);
    } else {
        if (t < NG) { gsum[t] = 0.f; gcnt[t] = 0.f; }
        a[t] = (t < NBUCK) ? bucketTot[t] : 0;
        __syncthreads();
        for (int off = 1; off < 1024; off <<= 1) {
            int x = a[t] + ((t >= off) ? a[t - off] : 0);
            __syncthreads();
            a[t] = x;
            __syncthreads();
        }
        if (t < NBUCK) bucketBase[t] = (t ? a[t - 1] : 0);
        if (t == 0) { bucketBase[NBUCK] = a[1023]; offs[NN] = a[1023]; }
    }
}

// scatter packed (src<<8 | dst&255) into bucket-partitioned pairs array
__global__ __launch_bounds__(512) void k_bscatter(const int* __restrict__ src,
                                                  const int* __restrict__ dst,
                                                  const int* __restrict__ blockCnt,
                                                  const int* __restrict__ bucketBase,
                                                  int* __restrict__ pairs) {
    __shared__ int cur[NBUCK];
    int t = threadIdx.x;
    for (int i = t; i < NBUCK; i += 512)
        cur[i] = blockCnt[i * NBLKE + blockIdx.x] + bucketBase[i];
    __syncthreads();
    int base = blockIdx.x * EPB;
    int n4 = (min(base + EPB, NE) - base) >> 2;
    const int4* d4 = (const int4*)(dst + base);
    const int4* s4 = (const int4*)(src + base);
    for (int i = t; i < n4; i += 512) {
        int4 dv = d4[i];
        int4 sv = s4[i];
        int p0 = atomicAdd(&cur[dv.x >> 8], 1);
        pairs[p0] = (sv.x << 8) | (dv.x & 255);
        int p1 = atomicAdd(&cur[dv.y >> 8], 1);
        pairs[p1] = (sv.y << 8) | (dv.y & 255);
        int p2 = atomicAdd(&cur[dv.z >> 8], 1);
        pairs[p2] = (sv.z << 8) | (dv.z & 255);
        int p3 = atomicAdd(&cur[dv.w >> 8], 1);
        pairs[p3] = (sv.w << 8) | (dv.w & 255);
    }
}

// one block per bucket: dual-replicated node hist; scan -> offs; fill into LDS
// (csr streamed out coalesced after); conv1: 2 threads/node x-gather + GEMV +
// fp8 store.
__global__ __launch_bounds__(512) void k_fill2c1(
    const int* __restrict__ bucketBase, const int* __restrict__ pairs,
    const float* __restrict__ x,
    const float* __restrict__ W1l, const float* __restrict__ b1l,
    const float* __restrict__ W1r,
    int* __restrict__ offs, int* __restrict__ csr, uint* __restrict__ h8) {
    __shared__ int aH[2][256];
    __shared__ int a[256];
    __shared__ int lcur[256];
    __shared__ int lss[LMAX];
    __shared__ float ps0[512], ps1[512];
    int t = threadIdx.x, b = blockIdx.x;
    int pb = bucketBase[b], pe = bucketBase[b + 1];
    if (t < 256) { aH[0][t] = 0; aH[1][t] = 0; }
    __syncthreads();
    int wp = (t >> 6) & 1;                       // wave-parity histogram copy
    for (int e = pb + t; e < pe; e += 512)
        atomicAdd(&aH[wp][pairs[e] & 255], 1);
    __syncthreads();
    if (t < 256) a[t] = aH[0][t] + aH[1][t];
    __syncthreads();
    for (int off = 1; off < 256; off <<= 1) {
        int v = 0;
        if (t < 256) v = a[t] + ((t >= off) ? a[t - off] : 0);
        __syncthreads();
        if (t < 256) a[t] = v;
        __syncthreads();
    }
    if (t < 256) lcur[t] = t ? a[t - 1] : 0;    // bucket-local cursor
    __syncthreads();
    // fill: LDS-only in the atomic loop (global csr streamed after)
    for (int e = pb + t; e < pe; e += 512) {
        int v = pairs[e];
        int s = v >> 8, dl = v & 255;
        int lpos = atomicAdd(&lcur[dl], 1);
        if (lpos < LMAX) lss[lpos] = s;
        else csr[pb + lpos] = s;                 // 23-sigma overflow path
    }
    __syncthreads();
    int tot = pe - pb;
    int totL = min(tot, LMAX);
    for (int idx = t; idx < totL; idx += 512)    // coalesced csr writeout
        csr[pb + idx] = lss[idx];
    // 2 threads per node gather x[src] partial sums (reads lss/csr)
    {
        int node8 = t & 255;
        int half = t >> 8;
        int excl = node8 ? a[node8 - 1] : 0;
        int cntn = a[node8] - excl;
        float s0 = 0.f, s1 = 0.f;
        for (int k = half; k < cntn; k += 2) {
            int idx = excl + k;
            int s = (idx < LMAX) ? lss[idx] : csr[pb + idx];
            float2 xv = *(const float2*)(x + 2 * s);
            s0 += xv.x; s1 += xv.y;
        }
        ps0[t] = s0; ps1[t] = s1;
    }
    __syncthreads();
    if (t < 256) {
        int node = b * 256 + t;
        if (node < NN) {
            int excl = t ? a[t - 1] : 0;
            int cntn = a[t] - excl;
            offs[node] = pb + excl;
            float inv = 1.0f / fmaxf((float)cntn, 1.0f);
            float m0 = (ps0[t] + ps0[t + 256]) * inv;
            float m1 = (ps1[t] + ps1[t + 256]) * inv;
            float x0 = x[2 * node], x1 = x[2 * node + 1];
            float o[16];
#pragma unroll
            for (int h = 0; h < 16; ++h)
                o[h] = fmaxf(m0 * W1l[h] + m1 * W1l[16 + h] + b1l[h]
                           + x0 * W1r[h] + x1 * W1r[16 + h], 0.f);
            uint4 w;
            w.x = packfp8x2<false>(o[0],  o[1],  0u);
            w.x = packfp8x2<true >(o[2],  o[3],  w.x);
            w.y = packfp8x2<false>(o[4],  o[5],  0u);
            w.y = packfp8x2<true >(o[6],  o[7],  w.y);
            w.z = packfp8x2<false>(o[8],  o[9],  0u);
            w.z = packfp8x2<true >(o[10], o[11], w.z);
            w.w = packfp8x2<false>(o[12], o[13], 0u);
            w.w = packfp8x2<true >(o[14], o[15], w.w);
            *(uint4*)(h8 + (size_t)node * 4) = w;
        }
    }
}

// conv2 + head + pool. 4 lanes/node, 64 nodes/block, fp8 16B rows:
// one 16B segment per edge-gather (16 rows per wave-load instruction).
__global__ __launch_bounds__(256) void k_conv2pool(
    const int* __restrict__ offs, const int* __restrict__ csr,
    const uint* __restrict__ h8,
    const float* __restrict__ W2l, const float* __restrict__ b2l,
    const float* __restrict__ W2r, const float* __restrict__ Wend,
    const float* __restrict__ bend, const int* __restrict__ batch,
    float* __restrict__ gsum, float* __restrict__ gcnt) {
    __shared__ float sWl[256], sWr[256], sB[HID], sWe[HID];
    __shared__ float sm[64][17], shr[64][17];
    __shared__ float ls[NG], lc[NG];
    int t = threadIdx.x;
    sWl[t] = W2l[t];
    sWr[t] = W2r[t];
    if (t < HID) { sB[t] = b2l[t]; sWe[t] = Wend[t]; }
    if (t < NG) { ls[t] = 0.f; lc[t] = 0.f; }

    int g = t >> 2;              // node slot 0..63
    int l4 = t & 3;
    int gbase = (t & 63) & 60;   // wave-relative base lane of 4-lane group
    int i = blockIdx.x * 64 + g;
    int beg = 0, end = 0;
    if (i < NN) { beg = offs[i]; end = offs[i + 1]; }
    float a0 = 0.f, a1 = 0.f, a2 = 0.f, a3 = 0.f;
    int kb = beg;
    uint ub[8];
    for (; kb + 8 <= end; kb += 8) {
        int sv0 = csr[kb + l4];
        int sv1 = csr[kb + 4 + l4];
#pragma unroll
        for (int j = 0; j < 4; ++j) {
            int s = __shfl(sv0, gbase + j, 64);
            ub[j] = h8[(size_t)s * 4 + l4];
        }
#pragma unroll
        for (int j = 0; j < 4; ++j) {
            int s = __shfl(sv1, gbase + j, 64);
            ub[4 + j] = h8[(size_t)s * 4 + l4];
        }
#pragma unroll
        for (int j = 0; j < 8; ++j) {
            vf2 p0 = dec2fp8<false>(ub[j]);
            vf2 p1 = dec2fp8<true >(ub[j]);
            a0 += p0.x; a1 += p0.y; a2 += p1.x; a3 += p1.y;
        }
    }
    for (; kb + 4 <= end; kb += 4) {
        int sv = csr[kb + l4];
#pragma unroll
        for (int j = 0; j < 4; ++j) {
            int s = __shfl(sv, gbase + j, 64);
            ub[j] = h8[(size_t)s * 4 + l4];
        }
#pragma unroll
        for (int j = 0; j < 4; ++j) {
            vf2 p0 = dec2fp8<false>(ub[j]);
            vf2 p1 = dec2fp8<true >(ub[j]);
            a0 += p0.x; a1 += p0.y; a2 += p1.x; a3 += p1.y;
        }
    }
    if (kb < end) {
        int idx = kb + l4;
        int sv = (idx < end) ? csr[idx] : 0;
        int nb = end - kb;
        for (int j = 0; j < nb; ++j) {
            int s = __shfl(sv, gbase + j, 64);
            uint u = h8[(size_t)s * 4 + l4];
            vf2 p0 = dec2fp8<false>(u);
            vf2 p1 = dec2fp8<true >(u);
            a0 += p0.x; a1 += p0.y; a2 += p1.x; a3 += p1.y;
        }
    }
    if (i < NN) {
        float inv = 1.0f / fmaxf((float)(end - beg), 1.0f);
        uint us = h8[(size_t)i * 4 + l4];
        vf2 q0 = dec2fp8<false>(us);
        vf2 q1 = dec2fp8<true >(us);
        sm[g][4 * l4 + 0] = a0 * inv;
        sm[g][4 * l4 + 1] = a1 * inv;
        sm[g][4 * l4 + 2] = a2 * inv;
        sm[g][4 * l4 + 3] = a3 * inv;
        shr[g][4 * l4 + 0] = q0.x;
        shr[g][4 * l4 + 1] = q0.y;
        shr[g][4 * l4 + 2] = q1.x;
        shr[g][4 * l4 + 3] = q1.y;
    }
    __syncthreads();

    float y = 0.f;
    if (i < NN) {
#pragma unroll
        for (int k = 0; k < 4; ++k) {
            int h = 4 * l4 + k;
            float a = sB[h];
#pragma unroll
            for (int f = 0; f < HID; ++f)
                a += sm[g][f] * sWl[f * HID + h] + shr[g][f] * sWr[f * HID + h];
            y += fmaxf(a, 0.f) * sWe[h];
        }
    }
    y += __shfl_xor(y, 1, 64);
    y += __shfl_xor(y, 2, 64);
    if (l4 == 0 && i < NN) {
        int bg = batch[i];
        atomicAdd(&ls[bg], y + bend[0]);
        atomicAdd(&lc[bg], 1.0f);
    }
    __syncthreads();
    if (t < NG && lc[t] != 0.0f) {
        unsafeAtomicAdd(&gsum[t], ls[t]);
        unsafeAtomicAdd(&gcnt[t], lc[t]);
    }
}

__global__ void k_final(const float* __restrict__ gsum, const float* __restrict__ gcnt,
                        float* __restrict__ out) {
    int g = threadIdx.x;
    if (g < NG) {
        float p = gsum[g] / fmaxf(gcnt[g], 1.0f);
        out[g] = 1.0f / (1.0f + expf(-p));
    }
}

extern "C" void kernel_launch(void* const* d_in, const int* in_sizes, int n_in,
                              void* d_out, int out_size, void* d_ws, size_t ws_size,
                              hipStream_t stream) {
    const float* x    = (const float*)d_in[0];
    const int*   ei   = (const int*)d_in[1];
    const int*   batch= (const int*)d_in[2];
    const float* W1l  = (const float*)d_in[3];
    const float* b1l  = (const float*)d_in[4];
    const float* W1r  = (const float*)d_in[5];
    const float* W2l  = (const float*)d_in[6];
    const float* b2l  = (const float*)d_in[7];
    const float* W2r  = (const float*)d_in[8];
    const float* Wend = (const float*)d_in[9];
    const float* bend = (const float*)d_in[10];

    const int* src = ei;        // edge_index[0]
    const int* dst = ei + NE;   // edge_index[1]

    float* gsum      = (float*)d_ws;
    float* gcnt      = (float*)d_ws + NG;
    int*   blockCnt  = (int*)d_ws + 2 * NG;
    int*   bucketTot = blockCnt + (size_t)NBUCK * NBLKE;
    int*   bucketBase= bucketTot + NBUCK;
    int*   offs      = bucketBase + NBUCK + 1;
    size_t po        = (size_t)(offs - (int*)d_ws) + NN + 1;
    po               = (po + 3) & ~(size_t)3;            // 16B align
    int*   pairs     = (int*)d_ws + po;
    int*   csr       = pairs + NE;
    uint*  h8        = (uint*)(csr + NE);

    hipMemsetAsync(bucketTot, 0, NBUCK * sizeof(int), stream);
    k_bhist     <<<NBLKE, 512, 0, stream>>>(dst, blockCnt, bucketTot);
    k_scan      <<<NBUCK + 1, 1024, 0, stream>>>(blockCnt, bucketTot, bucketBase,
                                                 offs, gsum, gcnt);
    k_bscatter  <<<NBLKE, 512, 0, stream>>>(src, dst, blockCnt, bucketBase, pairs);
    k_fill2c1   <<<NBUCK, 512, 0, stream>>>(bucketBase, pairs, x, W1l, b1l, W1r,
                                            offs, csr, h8);
    k_conv2pool <<<(NN + 63) / 64, 256, 0, stream>>>(offs, csr, h8, W2l, b2l, W2r,
                                                     Wend, bend, batch, gsum, gcnt);
    k_final     <<<1, 64, 0, stream>>>(gsum, gcnt, (float*)d_out);
}

// Round 16
// 105.009 us; speedup vs baseline: 1.2086x; 1.2086x over previous
//
#include <hip/hip_runtime.h>
#include <math.h>

#define NN 100000     // nodes
#define NE 3200000    // edges
#define NG 64         // graphs
#define HID 16
#define EPB 8192                          // edges per block in bucket pipeline
#define NBLKE ((NE + EPB - 1) / EPB)      // 391 edge blocks
#define NBUCK ((NN + 255) / 256)          // 391 buckets (256 nodes each)
#define LMAX 10240                        // per-bucket LDS sorted-src capacity

typedef unsigned int uint;
typedef float vf2 __attribute__((ext_vector_type(2)));

// ---------------- workspace layout (4-byte units) ----------------
// gsum      [0, NG)                     float  (zeroed by k_basescan)
// gcnt      [NG, 2NG)                   float  (zeroed by k_basescan)
// blockCnt  [2NG, +NBUCK*NBLKE)         int    (layout [bucket][blk])
// bucketTot [.., +NBUCK)                int
// bucketBase[.., +NBUCK+1)              int
// offs      [.., +NN+1)                 int    (node CSR offsets; [NN]=NE sentinel)
// pad to 16B
// pairs     [.., +NE)                   int    ((src<<8)|dst_low8, bucket-sorted)
// csr       [.., +NE)                   int    (src ids grouped by dst)
// h8        [.., +4*NN)                 uint   (h1 relu'd, fp8 e4m3 x16, 16B/row)
//
// BEST MEASURED: this exact configuration = 105.5us (round 8).
// LESSONS (all measured regressions vs this config):
//  - __threadfence in hot kernels: +100us (device-scope L2 writeback, r9)
//  - nontemporal stores on randomly-ordered fills: 13x write amp (r10)
//  - nontemporal loads on streams: net-negative here (r11)
//  - block-local sort instead of global 2-level: +11us (r12/r13)
//  - EPB 4096 instead of 8192: +4us (r14)
//  - merged scan + LDS-only fill + dual hist bundle: +17us (r15)

// ---------- fp8 e4m3 helpers (HW builtins; word-select must be literal) ----------
template <bool HI>
__device__ inline vf2 dec2fp8(uint u) {
#if __has_builtin(__builtin_amdgcn_cvt_pk_f32_fp8)
    return __builtin_amdgcn_cvt_pk_f32_fp8((int)u, HI);
#else
    vf2 r;
    uint b0 = (u >> (HI ? 16 : 0)) & 0xff;
    uint b1 = (u >> (HI ? 24 : 8)) & 0xff;
    uint em0 = b0 & 0x7f, em1 = b1 & 0x7f;
    float v0 = (em0 >= 8) ? __uint_as_float(((em0 >> 3) + 120) << 23 | (em0 & 7) << 20)
                          : (float)em0 * 0.001953125f;
    float v1 = (em1 >= 8) ? __uint_as_float(((em1 >> 3) + 120) << 23 | (em1 & 7) << 20)
                          : (float)em1 * 0.001953125f;
    r.x = (b0 & 0x80) ? -v0 : v0;
    r.y = (b1 & 0x80) ? -v1 : v1;
    return r;
#endif
}

__device__ inline uint enc1fp8(float f) {   // f >= 0 (post-relu)
    if (!(f > 0.f)) return 0u;
    f = fminf(f, 448.f);
    uint b = __float_as_uint(f);
    int e = (int)(b >> 23) - 127;
    if (e >= -6) {
        uint m = b & 0x7fffffu;
        uint r = (m + 0x7ffffu + ((m >> 20) & 1u)) >> 20;   // RNE to 3 bits
        uint code = ((uint)(e + 7) << 3) + r;               // carry ok
        return code > 126u ? 126u : code;
    }
    float t = f * 512.f;
    return (uint)(t + 0.5f);
}

template <bool HI>
__device__ inline uint packfp8x2(float a, float b, uint old) {
#if __has_builtin(__builtin_amdgcn_cvt_pk_fp8_f32)
    return (uint)__builtin_amdgcn_cvt_pk_fp8_f32(a, b, (int)old, HI);
#else
    uint v = enc1fp8(a) | (enc1fp8(b) << 8);
    return HI ? ((old & 0x0000ffffu) | (v << 16)) : ((old & 0xffff0000u) | v);
#endif
}

__global__ __launch_bounds__(512) void k_bhist(const int* __restrict__ dst,
                                               int* __restrict__ blockCnt) {
    __shared__ int h[NBUCK];
    int t = threadIdx.x;
    for (int i = t; i < NBUCK; i += 512) h[i] = 0;
    __syncthreads();
    int base = blockIdx.x * EPB;
    int n4 = (min(base + EPB, NE) - base) >> 2;       // always divisible by 4
    const int4* d4 = (const int4*)(dst + base);
    for (int i = t; i < n4; i += 512) {
        int4 v = d4[i];
        atomicAdd(&h[v.x >> 8], 1);
        atomicAdd(&h[v.y >> 8], 1);
        atomicAdd(&h[v.z >> 8], 1);
        atomicAdd(&h[v.w >> 8], 1);
    }
    __syncthreads();
    for (int i = t; i < NBUCK; i += 512)
        blockCnt[i * NBLKE + blockIdx.x] = h[i];       // [bucket][blk]
}

// per-bucket: exclusive prefix over the 391 edge-blocks (in place) + bucket total
__global__ __launch_bounds__(512) void k_bucketscan(int* __restrict__ blockCnt,
                                                    int* __restrict__ bucketTot) {
    __shared__ int a[512];
    int t = threadIdx.x, b = blockIdx.x;
    a[t] = (t < NBLKE) ? blockCnt[b * NBLKE + t] : 0;  // coalesced
    __syncthreads();
    for (int off = 1; off < 512; off <<= 1) {
        int x = a[t] + ((t >= off) ? a[t - off] : 0);
        __syncthreads();
        a[t] = x;
        __syncthreads();
    }
    if (t < NBLKE) blockCnt[b * NBLKE + t] = (t ? a[t - 1] : 0);
    if (t == 0) bucketTot[b] = a[511];
}

// exclusive scan of bucket totals -> bucketBase; sentinel offs[NN]=NE;
// also zeroes gsum/gcnt (replaces the hipMemsetAsync dispatch)
__global__ __launch_bounds__(512) void k_basescan(const int* __restrict__ bucketTot,
                                                  int* __restrict__ bucketBase,
                                                  int* __restrict__ offs,
                                                  float* __restrict__ gsum,
                                                  float* __restrict__ gcnt) {
    __shared__ int a[512];
    int t = threadIdx.x;
    if (t < NG) { gsum[t] = 0.f; gcnt[t] = 0.f; }
    a[t] = (t < NBUCK) ? bucketTot[t] : 0;
    __syncthreads();
    for (int off = 1; off < 512; off <<= 1) {
        int x = a[t] + ((t >= off) ? a[t - off] : 0);
        __syncthreads();
        a[t] = x;
        __syncthreads();
    }
    if (t < NBUCK) bucketBase[t] = (t ? a[t - 1] : 0);
    if (t == 0) { bucketBase[NBUCK] = a[511]; offs[NN] = a[511]; }
}

// scatter packed (src<<8 | dst&255) into bucket-partitioned pairs array
__global__ __launch_bounds__(512) void k_bscatter(const int* __restrict__ src,
                                                  const int* __restrict__ dst,
                                                  const int* __restrict__ blockCnt,
                                                  const int* __restrict__ bucketBase,
                                                  int* __restrict__ pairs) {
    __shared__ int cur[NBUCK];
    int t = threadIdx.x;
    for (int i = t; i < NBUCK; i += 512)
        cur[i] = blockCnt[i * NBLKE + blockIdx.x] + bucketBase[i];
    __syncthreads();
    int base = blockIdx.x * EPB;
    int n4 = (min(base + EPB, NE) - base) >> 2;
    const int4* d4 = (const int4*)(dst + base);
    const int4* s4 = (const int4*)(src + base);
    for (int i = t; i < n4; i += 512) {
        int4 dv = d4[i];
        int4 sv = s4[i];
        int p0 = atomicAdd(&cur[dv.x >> 8], 1);
        pairs[p0] = (sv.x << 8) | (dv.x & 255);
        int p1 = atomicAdd(&cur[dv.y >> 8], 1);
        pairs[p1] = (sv.y << 8) | (dv.y & 255);
        int p2 = atomicAdd(&cur[dv.z >> 8], 1);
        pairs[p2] = (sv.z << 8) | (dv.z & 255);
        int p3 = atomicAdd(&cur[dv.w >> 8], 1);
        pairs[p3] = (sv.w << 8) | (dv.w & 255);
    }
}

// one block per bucket: node hist+scan -> offs; csr fill (sorted srcs also kept
// in LDS); fused conv1 as per-node LDS segment sum + x gather + GEMV + fp8 store.
__global__ __launch_bounds__(512) void k_fill2c1(
    const int* __restrict__ bucketBase, const int* __restrict__ pairs,
    const float* __restrict__ x,
    const float* __restrict__ W1l, const float* __restrict__ b1l,
    const float* __restrict__ W1r,
    int* __restrict__ offs, int* __restrict__ csr, uint* __restrict__ h8) {
    __shared__ int a[256];
    __shared__ int lcur[256];
    __shared__ int lss[LMAX];
    int t = threadIdx.x, b = blockIdx.x;
    int pb = bucketBase[b], pe = bucketBase[b + 1];
    if (t < 256) a[t] = 0;
    __syncthreads();
    for (int e = pb + t; e < pe; e += 512)
        atomicAdd(&a[pairs[e] & 255], 1);
    __syncthreads();
    for (int off = 1; off < 256; off <<= 1) {
        int v = 0;
        if (t < 256) v = a[t] + ((t >= off) ? a[t - off] : 0);
        __syncthreads();
        if (t < 256) a[t] = v;
        __syncthreads();
    }
    if (t < 256) lcur[t] = t ? a[t - 1] : 0;    // bucket-local cursor
    __syncthreads();
    for (int e = pb + t; e < pe; e += 512) {
        int v = pairs[e];
        int s = v >> 8, dl = v & 255;
        int lpos = atomicAdd(&lcur[dl], 1);
        csr[pb + lpos] = s;
        if (lpos < LMAX) lss[lpos] = s;
    }
    __syncthreads();
    if (t < 256) {
        int node = b * 256 + t;
        if (node < NN) {
            int excl = t ? a[t - 1] : 0;
            int cntn = a[t] - excl;
            offs[node] = pb + excl;
            float s0 = 0.f, s1 = 0.f;
            for (int k = 0; k < cntn; ++k) {
                int idx = excl + k;
                int s = (idx < LMAX) ? lss[idx] : csr[pb + idx];
                float2 xv = *(const float2*)(x + 2 * s);
                s0 += xv.x; s1 += xv.y;
            }
            float inv = 1.0f / fmaxf((float)cntn, 1.0f);
            float m0 = s0 * inv, m1 = s1 * inv;
            float x0 = x[2 * node], x1 = x[2 * node + 1];
            float o[16];
#pragma unroll
            for (int h = 0; h < 16; ++h)
                o[h] = fmaxf(m0 * W1l[h] + m1 * W1l[16 + h] + b1l[h]
                           + x0 * W1r[h] + x1 * W1r[16 + h], 0.f);
            uint4 w;
            w.x = packfp8x2<false>(o[0],  o[1],  0u);
            w.x = packfp8x2<true >(o[2],  o[3],  w.x);
            w.y = packfp8x2<false>(o[4],  o[5],  0u);
            w.y = packfp8x2<true >(o[6],  o[7],  w.y);
            w.z = packfp8x2<false>(o[8],  o[9],  0u);
            w.z = packfp8x2<true >(o[10], o[11], w.z);
            w.w = packfp8x2<false>(o[12], o[13], 0u);
            w.w = packfp8x2<true >(o[14], o[15], w.w);
            *(uint4*)(h8 + (size_t)node * 4) = w;
        }
    }
}

// conv2 + head + pool. 4 lanes/node, 64 nodes/block, fp8 16B rows:
// one 16B segment per edge-gather (16 rows per wave-load instruction).
__global__ __launch_bounds__(256) void k_conv2pool(
    const int* __restrict__ offs, const int* __restrict__ csr,
    const uint* __restrict__ h8,
    const float* __restrict__ W2l, const float* __restrict__ b2l,
    const float* __restrict__ W2r, const float* __restrict__ Wend,
    const float* __restrict__ bend, const int* __restrict__ batch,
    float* __restrict__ gsum, float* __restrict__ gcnt) {
    __shared__ float sWl[256], sWr[256], sB[HID], sWe[HID];
    __shared__ float sm[64][17], shr[64][17];
    __shared__ float ls[NG], lc[NG];
    int t = threadIdx.x;
    sWl[t] = W2l[t];
    sWr[t] = W2r[t];
    if (t < HID) { sB[t] = b2l[t]; sWe[t] = Wend[t]; }
    if (t < NG) { ls[t] = 0.f; lc[t] = 0.f; }

    int g = t >> 2;              // node slot 0..63
    int l4 = t & 3;
    int gbase = (t & 63) & 60;   // wave-relative base lane of 4-lane group
    int i = blockIdx.x * 64 + g;
    int beg = 0, end = 0;
    if (i < NN) { beg = offs[i]; end = offs[i + 1]; }
    float a0 = 0.f, a1 = 0.f, a2 = 0.f, a3 = 0.f;
    int kb = beg;
    uint ub[8];
    for (; kb + 8 <= end; kb += 8) {
        int sv0 = csr[kb + l4];
        int sv1 = csr[kb + 4 + l4];
#pragma unroll
        for (int j = 0; j < 4; ++j) {
            int s = __shfl(sv0, gbase + j, 64);
            ub[j] = h8[(size_t)s * 4 + l4];
        }
#pragma unroll
        for (int j = 0; j < 4; ++j) {
            int s = __shfl(sv1, gbase + j, 64);
            ub[4 + j] = h8[(size_t)s * 4 + l4];
        }
#pragma unroll
        for (int j = 0; j < 8; ++j) {
            vf2 p0 = dec2fp8<false>(ub[j]);
            vf2 p1 = dec2fp8<true >(ub[j]);
            a0 += p0.x; a1 += p0.y; a2 += p1.x; a3 += p1.y;
        }
    }
    for (; kb + 4 <= end; kb += 4) {
        int sv = csr[kb + l4];
#pragma unroll
        for (int j = 0; j < 4; ++j) {
            int s = __shfl(sv, gbase + j, 64);
            ub[j] = h8[(size_t)s * 4 + l4];
        }
#pragma unroll
        for (int j = 0; j < 4; ++j) {
            vf2 p0 = dec2fp8<false>(ub[j]);
            vf2 p1 = dec2fp8<true >(ub[j]);
            a0 += p0.x; a1 += p0.y; a2 += p1.x; a3 += p1.y;
        }
    }
    if (kb < end) {
        int idx = kb + l4;
        int sv = (idx < end) ? csr[idx] : 0;
        int nb = end - kb;
        for (int j = 0; j < nb; ++j) {
            int s = __shfl(sv, gbase + j, 64);
            uint u = h8[(size_t)s * 4 + l4];
            vf2 p0 = dec2fp8<false>(u);
            vf2 p1 = dec2fp8<true >(u);
            a0 += p0.x; a1 += p0.y; a2 += p1.x; a3 += p1.y;
        }
    }
    if (i < NN) {
        float inv = 1.0f / fmaxf((float)(end - beg), 1.0f);
        uint us = h8[(size_t)i * 4 + l4];
        vf2 q0 = dec2fp8<false>(us);
        vf2 q1 = dec2fp8<true >(us);
        sm[g][4 * l4 + 0] = a0 * inv;
        sm[g][4 * l4 + 1] = a1 * inv;
        sm[g][4 * l4 + 2] = a2 * inv;
        sm[g][4 * l4 + 3] = a3 * inv;
        shr[g][4 * l4 + 0] = q0.x;
        shr[g][4 * l4 + 1] = q0.y;
        shr[g][4 * l4 + 2] = q1.x;
        shr[g][4 * l4 + 3] = q1.y;
    }
    __syncthreads();

    float y = 0.f;
    if (i < NN) {
#pragma unroll
        for (int k = 0; k < 4; ++k) {
            int h = 4 * l4 + k;
            float a = sB[h];
#pragma unroll
            for (int f = 0; f < HID; ++f)
                a += sm[g][f] * sWl[f * HID + h] + shr[g][f] * sWr[f * HID + h];
            y += fmaxf(a, 0.f) * sWe[h];
        }
    }
    y += __shfl_xor(y, 1, 64);
    y += __shfl_xor(y, 2, 64);
    if (l4 == 0 && i < NN) {
        int bg = batch[i];
        atomicAdd(&ls[bg], y + bend[0]);
        atomicAdd(&lc[bg], 1.0f);
    }
    __syncthreads();
    if (t < NG && lc[t] != 0.0f) {
        unsafeAtomicAdd(&gsum[t], ls[t]);
        unsafeAtomicAdd(&gcnt[t], lc[t]);
    }
}

__global__ void k_final(const float* __restrict__ gsum, const float* __restrict__ gcnt,
                        float* __restrict__ out) {
    int g = threadIdx.x;
    if (g < NG) {
        float p = gsum[g] / fmaxf(gcnt[g], 1.0f);
        out[g] = 1.0f / (1.0f + expf(-p));
    }
}

extern "C" void kernel_launch(void* const* d_in, const int* in_sizes, int n_in,
                              void* d_out, int out_size, void* d_ws, size_t ws_size,
                              hipStream_t stream) {
    const float* x    = (const float*)d_in[0];
    const int*   ei   = (const int*)d_in[1];
    const int*   batch= (const int*)d_in[2];
    const float* W1l  = (const float*)d_in[3];
    const float* b1l  = (const float*)d_in[4];
    const float* W1r  = (const float*)d_in[5];
    const float* W2l  = (const float*)d_in[6];
    const float* b2l  = (const float*)d_in[7];
    const float* W2r  = (const float*)d_in[8];
    const float* Wend = (const float*)d_in[9];
    const float* bend = (const float*)d_in[10];

    const int* src = ei;        // edge_index[0]
    const int* dst = ei + NE;   // edge_index[1]

    float* gsum      = (float*)d_ws;
    float* gcnt      = (float*)d_ws + NG;
    int*   blockCnt  = (int*)d_ws + 2 * NG;
    int*   bucketTot = blockCnt + (size_t)NBUCK * NBLKE;
    int*   bucketBase= bucketTot + NBUCK;
    int*   offs      = bucketBase + NBUCK + 1;
    size_t po        = (size_t)(offs - (int*)d_ws) + NN + 1;
    po               = (po + 3) & ~(size_t)3;            // 16B align
    int*   pairs     = (int*)d_ws + po;
    int*   csr       = pairs + NE;
    uint*  h8        = (uint*)(csr + NE);

    k_bhist     <<<NBLKE, 512, 0, stream>>>(dst, blockCnt);
    k_bucketscan<<<NBUCK, 512, 0, stream>>>(blockCnt, bucketTot);
    k_basescan  <<<1, 512, 0, stream>>>(bucketTot, bucketBase, offs, gsum, gcnt);
    k_bscatter  <<<NBLKE, 512, 0, stream>>>(src, dst, blockCnt, bucketBase, pairs);
    k_fill2c1   <<<NBUCK, 512, 0, stream>>>(bucketBase, pairs, x, W1l, b1l, W1r,
                                            offs, csr, h8);
    k_conv2pool <<<(NN + 63) / 64, 256, 0, stream>>>(offs, csr, h8, W2l, b2l, W2r,
                                                     Wend, bend, batch, gsum, gcnt);
    k_final     <<<1, 64, 0, stream>>>(gsum, gcnt, (float*)d_out);
}

// Round 17
// 104.736 us; speedup vs baseline: 1.2118x; 1.0026x over previous
//
#include <hip/hip_runtime.h>
#include <math.h>

#define NN 100000     // nodes
#define NE 3200000    // edges
#define NG 64         // graphs
#define HID 16
#define EPB 8192                          // edges per block in bucket pipeline
#define NBLKE ((NE + EPB - 1) / EPB)      // 391 edge blocks
#define NBUCK ((NN + 255) / 256)          // 391 buckets (256 nodes each)
#define LMAX 10240                        // per-bucket LDS sorted-src capacity

typedef unsigned int uint;
typedef float vf2 __attribute__((ext_vector_type(2)));

// ---------------- workspace layout (4-byte units) ----------------
// gsum      [0, NG)                     float  (zeroed by k_basescan)
// gcnt      [NG, 2NG)                   float  (zeroed by k_basescan)
// blockCnt  [2NG, +NBUCK*NBLKE)         int    (layout [bucket][blk])
// bucketTot [.., +NBUCK)                int
// bucketBase[.., +NBUCK+1)              int
// offs      [.., +NN+1)                 int    (node CSR offsets; [NN]=NE sentinel)
// pad to 16B
// pairs     [.., +NE)                   int    ((src<<8)|dst_low8, bucket-sorted)
// csr       [.., +NE)                   int    (src ids grouped by dst)
// h8        [.., +4*NN)                 uint   (h1 relu'd, fp8 e4m3 x16, 16B/row)
//
// BEST MEASURED: r16 config = 105.0us. This round: + 2-thread/node conv1
// x-gather in fill2c1 (the one unisolated candidate from r8's bundle).
// LESSONS (measured regressions): __threadfence in hot kernels +100us (r9);
// nontemporal stores on random fills 13x write amp (r10); nt loads negative
// (r11); block-local sort +11us (r12/r13); EPB=4096 +4us (r14); merged-scan
// bundle +17us (r15).

// ---------- fp8 e4m3 helpers (HW builtins; word-select must be literal) ----------
template <bool HI>
__device__ inline vf2 dec2fp8(uint u) {
#if __has_builtin(__builtin_amdgcn_cvt_pk_f32_fp8)
    return __builtin_amdgcn_cvt_pk_f32_fp8((int)u, HI);
#else
    vf2 r;
    uint b0 = (u >> (HI ? 16 : 0)) & 0xff;
    uint b1 = (u >> (HI ? 24 : 8)) & 0xff;
    uint em0 = b0 & 0x7f, em1 = b1 & 0x7f;
    float v0 = (em0 >= 8) ? __uint_as_float(((em0 >> 3) + 120) << 23 | (em0 & 7) << 20)
                          : (float)em0 * 0.001953125f;
    float v1 = (em1 >= 8) ? __uint_as_float(((em1 >> 3) + 120) << 23 | (em1 & 7) << 20)
                          : (float)em1 * 0.001953125f;
    r.x = (b0 & 0x80) ? -v0 : v0;
    r.y = (b1 & 0x80) ? -v1 : v1;
    return r;
#endif
}

__device__ inline uint enc1fp8(float f) {   // f >= 0 (post-relu)
    if (!(f > 0.f)) return 0u;
    f = fminf(f, 448.f);
    uint b = __float_as_uint(f);
    int e = (int)(b >> 23) - 127;
    if (e >= -6) {
        uint m = b & 0x7fffffu;
        uint r = (m + 0x7ffffu + ((m >> 20) & 1u)) >> 20;   // RNE to 3 bits
        uint code = ((uint)(e + 7) << 3) + r;               // carry ok
        return code > 126u ? 126u : code;
    }
    float t = f * 512.f;
    return (uint)(t + 0.5f);
}

template <bool HI>
__device__ inline uint packfp8x2(float a, float b, uint old) {
#if __has_builtin(__builtin_amdgcn_cvt_pk_fp8_f32)
    return (uint)__builtin_amdgcn_cvt_pk_fp8_f32(a, b, (int)old, HI);
#else
    uint v = enc1fp8(a) | (enc1fp8(b) << 8);
    return HI ? ((old & 0x0000ffffu) | (v << 16)) : ((old & 0xffff0000u) | v);
#endif
}

__global__ __launch_bounds__(512) void k_bhist(const int* __restrict__ dst,
                                               int* __restrict__ blockCnt) {
    __shared__ int h[NBUCK];
    int t = threadIdx.x;
    for (int i = t; i < NBUCK; i += 512) h[i] = 0;
    __syncthreads();
    int base = blockIdx.x * EPB;
    int n4 = (min(base + EPB, NE) - base) >> 2;       // always divisible by 4
    const int4* d4 = (const int4*)(dst + base);
    for (int i = t; i < n4; i += 512) {
        int4 v = d4[i];
        atomicAdd(&h[v.x >> 8], 1);
        atomicAdd(&h[v.y >> 8], 1);
        atomicAdd(&h[v.z >> 8], 1);
        atomicAdd(&h[v.w >> 8], 1);
    }
    __syncthreads();
    for (int i = t; i < NBUCK; i += 512)
        blockCnt[i * NBLKE + blockIdx.x] = h[i];       // [bucket][blk]
}

// per-bucket: exclusive prefix over the 391 edge-blocks (in place) + bucket total
__global__ __launch_bounds__(512) void k_bucketscan(int* __restrict__ blockCnt,
                                                    int* __restrict__ bucketTot) {
    __shared__ int a[512];
    int t = threadIdx.x, b = blockIdx.x;
    a[t] = (t < NBLKE) ? blockCnt[b * NBLKE + t] : 0;  // coalesced
    __syncthreads();
    for (int off = 1; off < 512; off <<= 1) {
        int x = a[t] + ((t >= off) ? a[t - off] : 0);
        __syncthreads();
        a[t] = x;
        __syncthreads();
    }
    if (t < NBLKE) blockCnt[b * NBLKE + t] = (t ? a[t - 1] : 0);
    if (t == 0) bucketTot[b] = a[511];
}

// exclusive scan of bucket totals -> bucketBase; sentinel offs[NN]=NE;
// also zeroes gsum/gcnt (replaces the hipMemsetAsync dispatch)
__global__ __launch_bounds__(512) void k_basescan(const int* __restrict__ bucketTot,
                                                  int* __restrict__ bucketBase,
                                                  int* __restrict__ offs,
                                                  float* __restrict__ gsum,
                                                  float* __restrict__ gcnt) {
    __shared__ int a[512];
    int t = threadIdx.x;
    if (t < NG) { gsum[t] = 0.f; gcnt[t] = 0.f; }
    a[t] = (t < NBUCK) ? bucketTot[t] : 0;
    __syncthreads();
    for (int off = 1; off < 512; off <<= 1) {
        int x = a[t] + ((t >= off) ? a[t - off] : 0);
        __syncthreads();
        a[t] = x;
        __syncthreads();
    }
    if (t < NBUCK) bucketBase[t] = (t ? a[t - 1] : 0);
    if (t == 0) { bucketBase[NBUCK] = a[511]; offs[NN] = a[511]; }
}

// scatter packed (src<<8 | dst&255) into bucket-partitioned pairs array
__global__ __launch_bounds__(512) void k_bscatter(const int* __restrict__ src,
                                                  const int* __restrict__ dst,
                                                  const int* __restrict__ blockCnt,
                                                  const int* __restrict__ bucketBase,
                                                  int* __restrict__ pairs) {
    __shared__ int cur[NBUCK];
    int t = threadIdx.x;
    for (int i = t; i < NBUCK; i += 512)
        cur[i] = blockCnt[i * NBLKE + blockIdx.x] + bucketBase[i];
    __syncthreads();
    int base = blockIdx.x * EPB;
    int n4 = (min(base + EPB, NE) - base) >> 2;
    const int4* d4 = (const int4*)(dst + base);
    const int4* s4 = (const int4*)(src + base);
    for (int i = t; i < n4; i += 512) {
        int4 dv = d4[i];
        int4 sv = s4[i];
        int p0 = atomicAdd(&cur[dv.x >> 8], 1);
        pairs[p0] = (sv.x << 8) | (dv.x & 255);
        int p1 = atomicAdd(&cur[dv.y >> 8], 1);
        pairs[p1] = (sv.y << 8) | (dv.y & 255);
        int p2 = atomicAdd(&cur[dv.z >> 8], 1);
        pairs[p2] = (sv.z << 8) | (dv.z & 255);
        int p3 = atomicAdd(&cur[dv.w >> 8], 1);
        pairs[p3] = (sv.w << 8) | (dv.w & 255);
    }
}

// one block per bucket: node hist+scan -> offs; csr fill (sorted srcs also kept
// in LDS); fused conv1: 2-thread/node x segment-gather + GEMV + fp8 store.
__global__ __launch_bounds__(512) void k_fill2c1(
    const int* __restrict__ bucketBase, const int* __restrict__ pairs,
    const float* __restrict__ x,
    const float* __restrict__ W1l, const float* __restrict__ b1l,
    const float* __restrict__ W1r,
    int* __restrict__ offs, int* __restrict__ csr, uint* __restrict__ h8) {
    __shared__ int a[256];
    __shared__ int lcur[256];
    __shared__ int lss[LMAX];
    __shared__ float ps0[512], ps1[512];
    int t = threadIdx.x, b = blockIdx.x;
    int pb = bucketBase[b], pe = bucketBase[b + 1];
    if (t < 256) a[t] = 0;
    __syncthreads();
    for (int e = pb + t; e < pe; e += 512)
        atomicAdd(&a[pairs[e] & 255], 1);
    __syncthreads();
    for (int off = 1; off < 256; off <<= 1) {
        int v = 0;
        if (t < 256) v = a[t] + ((t >= off) ? a[t - off] : 0);
        __syncthreads();
        if (t < 256) a[t] = v;
        __syncthreads();
    }
    if (t < 256) lcur[t] = t ? a[t - 1] : 0;    // bucket-local cursor
    __syncthreads();
    for (int e = pb + t; e < pe; e += 512) {
        int v = pairs[e];
        int s = v >> 8, dl = v & 255;
        int lpos = atomicAdd(&lcur[dl], 1);
        csr[pb + lpos] = s;
        if (lpos < LMAX) lss[lpos] = s;
    }
    __syncthreads();
    // 2 threads per node gather x[src] partial sums (all 512 threads active)
    {
        int node8 = t & 255;
        int half = t >> 8;
        int excl = node8 ? a[node8 - 1] : 0;
        int cntn = a[node8] - excl;
        float s0 = 0.f, s1 = 0.f;
        for (int k = half; k < cntn; k += 2) {
            int idx = excl + k;
            int s = (idx < LMAX) ? lss[idx] : csr[pb + idx];
            float2 xv = *(const float2*)(x + 2 * s);
            s0 += xv.x; s1 += xv.y;
        }
        ps0[t] = s0; ps1[t] = s1;
    }
    __syncthreads();
    if (t < 256) {
        int node = b * 256 + t;
        if (node < NN) {
            int excl = t ? a[t - 1] : 0;
            int cntn = a[t] - excl;
            offs[node] = pb + excl;
            float inv = 1.0f / fmaxf((float)cntn, 1.0f);
            float m0 = (ps0[t] + ps0[t + 256]) * inv;
            float m1 = (ps1[t] + ps1[t + 256]) * inv;
            float x0 = x[2 * node], x1 = x[2 * node + 1];
            float o[16];
#pragma unroll
            for (int h = 0; h < 16; ++h)
                o[h] = fmaxf(m0 * W1l[h] + m1 * W1l[16 + h] + b1l[h]
                           + x0 * W1r[h] + x1 * W1r[16 + h], 0.f);
            uint4 w;
            w.x = packfp8x2<false>(o[0],  o[1],  0u);
            w.x = packfp8x2<true >(o[2],  o[3],  w.x);
            w.y = packfp8x2<false>(o[4],  o[5],  0u);
            w.y = packfp8x2<true >(o[6],  o[7],  w.y);
            w.z = packfp8x2<false>(o[8],  o[9],  0u);
            w.z = packfp8x2<true >(o[10], o[11], w.z);
            w.w = packfp8x2<false>(o[12], o[13], 0u);
            w.w = packfp8x2<true >(o[14], o[15], w.w);
            *(uint4*)(h8 + (size_t)node * 4) = w;
        }
    }
}

// conv2 + head + pool. 4 lanes/node, 64 nodes/block, fp8 16B rows:
// one 16B segment per edge-gather (16 rows per wave-load instruction).
__global__ __launch_bounds__(256) void k_conv2pool(
    const int* __restrict__ offs, const int* __restrict__ csr,
    const uint* __restrict__ h8,
    const float* __restrict__ W2l, const float* __restrict__ b2l,
    const float* __restrict__ W2r, const float* __restrict__ Wend,
    const float* __restrict__ bend, const int* __restrict__ batch,
    float* __restrict__ gsum, float* __restrict__ gcnt) {
    __shared__ float sWl[256], sWr[256], sB[HID], sWe[HID];
    __shared__ float sm[64][17], shr[64][17];
    __shared__ float ls[NG], lc[NG];
    int t = threadIdx.x;
    sWl[t] = W2l[t];
    sWr[t] = W2r[t];
    if (t < HID) { sB[t] = b2l[t]; sWe[t] = Wend[t]; }
    if (t < NG) { ls[t] = 0.f; lc[t] = 0.f; }

    int g = t >> 2;              // node slot 0..63
    int l4 = t & 3;
    int gbase = (t & 63) & 60;   // wave-relative base lane of 4-lane group
    int i = blockIdx.x * 64 + g;
    int beg = 0, end = 0;
    if (i < NN) { beg = offs[i]; end = offs[i + 1]; }
    float a0 = 0.f, a1 = 0.f, a2 = 0.f, a3 = 0.f;
    int kb = beg;
    uint ub[8];
    for (; kb + 8 <= end; kb += 8) {
        int sv0 = csr[kb + l4];
        int sv1 = csr[kb + 4 + l4];
#pragma unroll
        for (int j = 0; j < 4; ++j) {
            int s = __shfl(sv0, gbase + j, 64);
            ub[j] = h8[(size_t)s * 4 + l4];
        }
#pragma unroll
        for (int j = 0; j < 4; ++j) {
            int s = __shfl(sv1, gbase + j, 64);
            ub[4 + j] = h8[(size_t)s * 4 + l4];
        }
#pragma unroll
        for (int j = 0; j < 8; ++j) {
            vf2 p0 = dec2fp8<false>(ub[j]);
            vf2 p1 = dec2fp8<true >(ub[j]);
            a0 += p0.x; a1 += p0.y; a2 += p1.x; a3 += p1.y;
        }
    }
    for (; kb + 4 <= end; kb += 4) {
        int sv = csr[kb + l4];
#pragma unroll
        for (int j = 0; j < 4; ++j) {
            int s = __shfl(sv, gbase + j, 64);
            ub[j] = h8[(size_t)s * 4 + l4];
        }
#pragma unroll
        for (int j = 0; j < 4; ++j) {
            vf2 p0 = dec2fp8<false>(ub[j]);
            vf2 p1 = dec2fp8<true >(ub[j]);
            a0 += p0.x; a1 += p0.y; a2 += p1.x; a3 += p1.y;
        }
    }
    if (kb < end) {
        int idx = kb + l4;
        int sv = (idx < end) ? csr[idx] : 0;
        int nb = end - kb;
        for (int j = 0; j < nb; ++j) {
            int s = __shfl(sv, gbase + j, 64);
            uint u = h8[(size_t)s * 4 + l4];
            vf2 p0 = dec2fp8<false>(u);
            vf2 p1 = dec2fp8<true >(u);
            a0 += p0.x; a1 += p0.y; a2 += p1.x; a3 += p1.y;
        }
    }
    if (i < NN) {
        float inv = 1.0f / fmaxf((float)(end - beg), 1.0f);
        uint us = h8[(size_t)i * 4 + l4];
        vf2 q0 = dec2fp8<false>(us);
        vf2 q1 = dec2fp8<true >(us);
        sm[g][4 * l4 + 0] = a0 * inv;
        sm[g][4 * l4 + 1] = a1 * inv;
        sm[g][4 * l4 + 2] = a2 * inv;
        sm[g][4 * l4 + 3] = a3 * inv;
        shr[g][4 * l4 + 0] = q0.x;
        shr[g][4 * l4 + 1] = q0.y;
        shr[g][4 * l4 + 2] = q1.x;
        shr[g][4 * l4 + 3] = q1.y;
    }
    __syncthreads();

    float y = 0.f;
    if (i < NN) {
#pragma unroll
        for (int k = 0; k < 4; ++k) {
            int h = 4 * l4 + k;
            float a = sB[h];
#pragma unroll
            for (int f = 0; f < HID; ++f)
                a += sm[g][f] * sWl[f * HID + h] + shr[g][f] * sWr[f * HID + h];
            y += fmaxf(a, 0.f) * sWe[h];
        }
    }
    y += __shfl_xor(y, 1, 64);
    y += __shfl_xor(y, 2, 64);
    if (l4 == 0 && i < NN) {
        int bg = batch[i];
        atomicAdd(&ls[bg], y + bend[0]);
        atomicAdd(&lc[bg], 1.0f);
    }
    __syncthreads();
    if (t < NG && lc[t] != 0.0f) {
        unsafeAtomicAdd(&gsum[t], ls[t]);
        unsafeAtomicAdd(&gcnt[t], lc[t]);
    }
}

__global__ void k_final(const float* __restrict__ gsum, const float* __restrict__ gcnt,
                        float* __restrict__ out) {
    int g = threadIdx.x;
    if (g < NG) {
        float p = gsum[g] / fmaxf(gcnt[g], 1.0f);
        out[g] = 1.0f / (1.0f + expf(-p));
    }
}

extern "C" void kernel_launch(void* const* d_in, const int* in_sizes, int n_in,
                              void* d_out, int out_size, void* d_ws, size_t ws_size,
                              hipStream_t stream) {
    const float* x    = (const float*)d_in[0];
    const int*   ei   = (const int*)d_in[1];
    const int*   batch= (const int*)d_in[2];
    const float* W1l  = (const float*)d_in[3];
    const float* b1l  = (const float*)d_in[4];
    const float* W1r  = (const float*)d_in[5];
    const float* W2l  = (const float*)d_in[6];
    const float* b2l  = (const float*)d_in[7];
    const float* W2r  = (const float*)d_in[8];
    const float* Wend = (const float*)d_in[9];
    const float* bend = (const float*)d_in[10];

    const int* src = ei;        // edge_index[0]
    const int* dst = ei + NE;   // edge_index[1]

    float* gsum      = (float*)d_ws;
    float* gcnt      = (float*)d_ws + NG;
    int*   blockCnt  = (int*)d_ws + 2 * NG;
    int*   bucketTot = blockCnt + (size_t)NBUCK * NBLKE;
    int*   bucketBase= bucketTot + NBUCK;
    int*   offs      = bucketBase + NBUCK + 1;
    size_t po        = (size_t)(offs - (int*)d_ws) + NN + 1;
    po               = (po + 3) & ~(size_t)3;            // 16B align
    int*   pairs     = (int*)d_ws + po;
    int*   csr       = pairs + NE;
    uint*  h8        = (uint*)(csr + NE);

    k_bhist     <<<NBLKE, 512, 0, stream>>>(dst, blockCnt);
    k_bucketscan<<<NBUCK, 512, 0, stream>>>(blockCnt, bucketTot);
    k_basescan  <<<1, 512, 0, stream>>>(bucketTot, bucketBase, offs, gsum, gcnt);
    k_bscatter  <<<NBLKE, 512, 0, stream>>>(src, dst, blockCnt, bucketBase, pairs);
    k_fill2c1   <<<NBUCK, 512, 0, stream>>>(bucketBase, pairs, x, W1l, b1l, W1r,
                                            offs, csr, h8);
    k_conv2pool <<<(NN + 63) / 64, 256, 0, stream>>>(offs, csr, h8, W2l, b2l, W2r,
                                                     Wend, bend, batch, gsum, gcnt);
    k_final     <<<1, 64, 0, stream>>>(gsum, gcnt, (float*)d_out);
}